// Round 1
// 256.424 us; speedup vs baseline: 1.0304x; 1.0304x over previous
//
#include <hip/hip_runtime.h>
#include <hip/hip_bf16.h>

typedef __bf16 bf16_t;
typedef __attribute__((ext_vector_type(8))) __bf16 bf16x8;
typedef __attribute__((ext_vector_type(4))) __bf16 bf16x4;
typedef __attribute__((ext_vector_type(4))) float f32x4;

#define N1 16384
#define N2 4096
#define C1 128
#define C2 256
#define CIN 384
#define HD1 256
#define HD2 128
#define BDIM 4
#define CHUNK 512
#define NCHUNK 8   // N2 / CHUNK
#define NCAND 24   // NCHUNK * 3

// ---- prep: transpose + cast weights to bf16 ([K][N] fp32 -> [N][K] bf16) ----
__global__ void prep_w(const float* __restrict__ W1, const float* __restrict__ W2,
                       bf16_t* __restrict__ W1t, bf16_t* __restrict__ W2t) {
  int tid = blockIdx.x * 256 + threadIdx.x;
  if (tid < CIN * HD1) {
    int k = tid / HD1, n = tid % HD1;
    W1t[n * CIN + k] = (bf16_t)W1[tid];
  }
  if (tid < HD1 * HD2) {
    int k = tid / HD2, n = tid % HD2;
    W2t[n * HD1 + k] = (bf16_t)W2[tid];
  }
}

// ---- per-chunk top-3: 256 queries/block x one 512-point chunk ----
// UNCHANGED from validated 264us version: VALUBusy 88-90%, 21.8 inst/cand vs
// ~19 floor -> at its VALU roofline for brute-force exact selection.
__global__ __launch_bounds__(256) void knn_chunk(
    const float* __restrict__ xyz1, const float* __restrict__ xyz2,
    float* __restrict__ candd, int* __restrict__ candj) {
  int b  = blockIdx.y;
  int ck = blockIdx.z;
  int i  = blockIdx.x * 256 + threadIdx.x;
  const float* p = xyz1 + ((size_t)b * N1 + i) * 3;
  float px = p[0], py = p[1], pz = p[2];

  const float* x2b = xyz2 + ((size_t)b * N2 + (size_t)ck * CHUNK) * 3;

  float d0 = 3.4e38f, d1 = 3.4e38f, d2 = 3.4e38f;
  int   j0 = 0, j1 = 0, j2 = 0;

  for (int j = 0; j < CHUNK; j += 16) {
    // 16 points = 48 floats, uniform addresses -> 3x s_load_dwordx16
    float c[48];
    const float4* q = (const float4*)(x2b + 3 * j);
#pragma unroll
    for (int t = 0; t < 12; ++t) {
      float4 v = q[t];
      c[4 * t + 0] = v.x; c[4 * t + 1] = v.y; c[4 * t + 2] = v.z; c[4 * t + 3] = v.w;
    }
#pragma unroll
    for (int u = 0; u < 16; ++u) {
      // (cx-px): negation-exact vs reference (px-cx); square identical ->
      // selection matches the fp32 reference bit-for-bit
      float dx = __fsub_rn(c[3 * u + 0], px);
      float dy = __fsub_rn(c[3 * u + 1], py);
      float dz = __fsub_rn(c[3 * u + 2], pz);
      float d = __fadd_rn(__fadd_rn(__fmul_rn(dx, dx), __fmul_rn(dy, dy)),
                          __fmul_rn(dz, dz));
      int jj = j + u;
      if (d < d2) {  // strict <: earlier index wins ties (matches top_k)
        bool lt0 = d < d0, lt1 = d < d1;
        j2 = lt1 ? j1 : jj;
        j1 = lt0 ? j0 : (lt1 ? jj : j1);
        j0 = lt0 ? jj : j0;
        d2 = __builtin_amdgcn_fmed3f(d, d1, d2);
        d1 = __builtin_amdgcn_fmed3f(d, d0, d1);
        d0 = fminf(d, d0);
      }
    }
  }
  size_t qb = ((size_t)b * N1 + i) * NCAND + (size_t)ck * 3;
  int jbase = ck * CHUNK;
  candd[qb + 0] = d0; candd[qb + 1] = d1; candd[qb + 2] = d2;
  candj[qb + 0] = j0 + jbase; candj[qb + 1] = j1 + jbase; candj[qb + 2] = j2 + jbase;
}

// ---- merge 8x3 candidates -> final top-3 + normalized weights ----
__global__ __launch_bounds__(256) void knn_merge(
    const float* __restrict__ candd, const int* __restrict__ candj,
    float* __restrict__ wq, int* __restrict__ iq) {
  int q = blockIdx.x * 256 + threadIdx.x;
  const float* cd = candd + (size_t)q * NCAND;
  const int*   cj = candj + (size_t)q * NCAND;
  float d0 = 3.4e38f, d1 = 3.4e38f, d2 = 3.4e38f;
  int   j0 = 0, j1 = 0, j2 = 0;
#pragma unroll
  for (int c = 0; c < NCAND; ++c) {
    float d = cd[c]; int j = cj[c];
    bool p0 = d < d0, p1 = d < d1, p2 = d < d2;
    j2 = p1 ? j1 : (p2 ? j : j2);
    j1 = p0 ? j0 : (p1 ? j : j1);
    j0 = p0 ? j : j0;
    d2 = __builtin_amdgcn_fmed3f(d, d1, d2);
    d1 = __builtin_amdgcn_fmed3f(d, d0, d1);
    d0 = fminf(d, d0);
  }
  d0 = fmaxf(d0, 1e-10f); d1 = fmaxf(d1, 1e-10f); d2 = fmaxf(d2, 1e-10f);
  float w0 = 1.0f / d0, w1 = 1.0f / d1, w2 = 1.0f / d2;
  float ws = w0 + w1 + w2;
  wq[q * 3 + 0] = w0 / ws; wq[q * 3 + 1] = w1 / ws; wq[q * 3 + 2] = w2 / ws;
  iq[q * 3 + 0] = j0; iq[q * 3 + 1] = j1; iq[q * 3 + 2] = j2;
}

// ---- FUSED interp+concat+GEMM1: H = relu(NF @ W1t^T + b1), NF never
// materialized. Block = 128 rows x 256 cols (full N: gather done once),
// BK=32, 12 K-steps. A-tile COMPUTED into LDS per step:
//   ks 0..7  -> 3-NN weighted gather from f2 (L2/L3-resident, 16.8 MB)
//   ks 8..11 -> f1 copy/cast (concat half)
// Same source expressions as the validated interp_concat -> NF bf16 values
// bit-identical; MFMA mapping/epilogue copied from validated gemm_bt -> H
// bit-identical. W1 staged per-step via global_load_lds(16) into k-octet-
// major Bs[quad][n][8] (wave-uniform LDS base + lane*16 contiguous).
__global__ __launch_bounds__(256, 2) void interp_gemm1(
    const float* __restrict__ f1, const float* __restrict__ f2,
    const float* __restrict__ wq, const int* __restrict__ iq,
    const bf16_t* __restrict__ W1t, const float* __restrict__ b1,
    bf16_t* __restrict__ Hbuf) {
  __shared__ __align__(16) bf16_t As[128 * 32];      // 8 KB  [row][32k]
  __shared__ __align__(16) bf16_t Bs[4 * 256 * 8];   // 16 KB [quad][n][8k]
  int tid  = threadIdx.x;
  int wv   = tid >> 6, ln = tid & 63;
  int quad = ln >> 4, lm = ln & 15;
  long row0 = (long)blockIdx.x * 128;

  // staging role: fixed row per thread pair, 16 cols per thread per step
  int srow = tid >> 1;
  int sh   = tid & 1;
  long q = row0 + srow;
  int  b = (int)(q >> 14);  // N1 = 2^14
  float u0 = wq[q * 3 + 0], u1 = wq[q * 3 + 1], u2 = wq[q * 3 + 2];
  const float* f2b = f2 + (size_t)b * N2 * C2;
  const float* r0 = f2b + (size_t)iq[q * 3 + 0] * C2;
  const float* r1 = f2b + (size_t)iq[q * 3 + 1] * C2;
  const float* r2 = f2b + (size_t)iq[q * 3 + 2] * C2;
  const float* f1r = f1 + (size_t)q * C1;
  bf16_t* asd = As + srow * 32 + sh * 16;

  // mfma role: wave tile 64 rows x 128 cols
  int wm = (wv >> 1) * 64, wn = (wv & 1) * 128;
  f32x4 acc[4][8] = {};

  for (int ks = 0; ks < 12; ++ks) {
    int kb = ks * 32;
    // --- stage W1 tile (issue DMA first so it flies under the gather) ---
#pragma unroll
    for (int s = 0; s < 4; ++s) {
      __builtin_amdgcn_global_load_lds(
          (const __attribute__((address_space(1))) void*)(
              W1t + (size_t)(wv * 64 + ln) * CIN + kb + s * 8),
          (__attribute__((address_space(3))) void*)(Bs + s * 2048 + wv * 512),
          16, 0, 0);
    }
    // --- compute A tile into LDS ---
    bf16x8 o[2];
    if (ks < 8) {
      int cb = kb + sh * 16;
#pragma unroll
      for (int c4 = 0; c4 < 4; ++c4) {
        float4 v0 = *(const float4*)(r0 + cb + c4 * 4);
        float4 v1 = *(const float4*)(r1 + cb + c4 * 4);
        float4 v2 = *(const float4*)(r2 + cb + c4 * 4);
        int oi = c4 >> 1, off = (c4 & 1) * 4;
        o[oi][off + 0] = (bf16_t)(u0 * v0.x + u1 * v1.x + u2 * v2.x);
        o[oi][off + 1] = (bf16_t)(u0 * v0.y + u1 * v1.y + u2 * v2.y);
        o[oi][off + 2] = (bf16_t)(u0 * v0.z + u1 * v1.z + u2 * v2.z);
        o[oi][off + 3] = (bf16_t)(u0 * v0.w + u1 * v1.w + u2 * v2.w);
      }
    } else {
      int cf = kb - 256 + sh * 16;
#pragma unroll
      for (int c4 = 0; c4 < 4; ++c4) {
        float4 g = *(const float4*)(f1r + cf + c4 * 4);
        int oi = c4 >> 1, off = (c4 & 1) * 4;
        o[oi][off + 0] = (bf16_t)g.x;
        o[oi][off + 1] = (bf16_t)g.y;
        o[oi][off + 2] = (bf16_t)g.z;
        o[oi][off + 3] = (bf16_t)g.w;
      }
    }
    *(bf16x8*)(asd) = o[0];
    *(bf16x8*)(asd + 8) = o[1];
    __syncthreads();

    // --- fragments + MFMA (identical mapping to validated gemm_bt) ---
    bf16x8 af[4];
#pragma unroll
    for (int mi = 0; mi < 4; ++mi)
      af[mi] = *(const bf16x8*)(As + (wm + mi * 16 + lm) * 32 + quad * 8);
#pragma unroll
    for (int nh = 0; nh < 2; ++nh) {
      bf16x8 bfr[4];
#pragma unroll
      for (int nn = 0; nn < 4; ++nn)
        bfr[nn] = *(const bf16x8*)(Bs + quad * 2048 + (wn + (nh * 4 + nn) * 16 + lm) * 8);
#pragma unroll
      for (int mi = 0; mi < 4; ++mi)
#pragma unroll
        for (int nn = 0; nn < 4; ++nn)
          acc[mi][nh * 4 + nn] = __builtin_amdgcn_mfma_f32_16x16x32_bf16(
              af[mi], bfr[nn], acc[mi][nh * 4 + nn], 0, 0, 0);
    }
    __syncthreads();
  }

#pragma unroll
  for (int mi = 0; mi < 4; ++mi)
#pragma unroll
    for (int ni = 0; ni < 8; ++ni) {
      int col = wn + ni * 16 + lm;
      float bv = b1[col];
#pragma unroll
      for (int r = 0; r < 4; ++r) {
        long rowg = row0 + wm + mi * 16 + quad * 4 + r;
        float v = acc[mi][ni][r] + bv;
        v = fmaxf(v, 0.0f);
        Hbuf[rowg * HD1 + col] = (bf16_t)v;
      }
    }
}

// ---- bf16 MFMA GEMM (validated): C = relu(A @ Bt^T + bias) ----
template <bool OUT_BF16>
__global__ __launch_bounds__(256) void gemm_bt(
    const bf16_t* __restrict__ A, const bf16_t* __restrict__ Bt,
    const float* __restrict__ bias, void* __restrict__ Cout,
    int M, int N, int K) {
  __shared__ __align__(16) bf16_t As[128 * 32];
  __shared__ __align__(16) bf16_t Bs[128 * 32];
  int tid  = threadIdx.x;
  int wv   = tid >> 6, ln = tid & 63;
  int quad = ln >> 4, lm = ln & 15;
  long row0 = (long)blockIdx.x * 128;
  int  col0 = blockIdx.y * 128;
  const bf16_t* Ab = A + row0 * K;
  const bf16_t* Bb = Bt + (long)col0 * K;
  f32x4 acc[4][4] = {};
  int wm = (wv >> 1) * 64, wn = (wv & 1) * 64;

  for (int k0 = 0; k0 < K; k0 += 32) {
#pragma unroll
    for (int t = 0; t < 2; ++t) {
      int c = t * 256 + tid;
      int r = c >> 2, kc = (c & 3) << 3;
      __builtin_amdgcn_global_load_lds(
          (const __attribute__((address_space(1))) void*)(Ab + (long)r * K + k0 + kc),
          (__attribute__((address_space(3))) void*)(As + (t * 256 + wv * 64) * 8),
          16, 0, 0);
      __builtin_amdgcn_global_load_lds(
          (const __attribute__((address_space(1))) void*)(Bb + (long)r * K + k0 + kc),
          (__attribute__((address_space(3))) void*)(Bs + (t * 256 + wv * 64) * 8),
          16, 0, 0);
    }
    __syncthreads();
    bf16x8 af[4], bfr[4];
#pragma unroll
    for (int mi = 0; mi < 4; ++mi)
      af[mi] = *(const bf16x8*)(As + (wm + mi * 16 + lm) * 32 + quad * 8);
#pragma unroll
    for (int ni = 0; ni < 4; ++ni)
      bfr[ni] = *(const bf16x8*)(Bs + (wn + ni * 16 + lm) * 32 + quad * 8);
#pragma unroll
    for (int mi = 0; mi < 4; ++mi)
#pragma unroll
      for (int ni = 0; ni < 4; ++ni)
        acc[mi][ni] = __builtin_amdgcn_mfma_f32_16x16x32_bf16(af[mi], bfr[ni],
                                                              acc[mi][ni], 0, 0, 0);
    __syncthreads();
  }

#pragma unroll
  for (int mi = 0; mi < 4; ++mi)
#pragma unroll
    for (int ni = 0; ni < 4; ++ni) {
      int col = col0 + wn + ni * 16 + lm;
      float bv = bias[col];
#pragma unroll
      for (int r = 0; r < 4; ++r) {
        long rowg = row0 + wm + mi * 16 + quad * 4 + r;
        float v = acc[mi][ni][r] + bv;
        v = fmaxf(v, 0.0f);
        if (OUT_BF16) ((bf16_t*)Cout)[rowg * N + col] = (bf16_t)v;
        else          ((float*)Cout)[rowg * N + col]  = v;
      }
    }
}

extern "C" void kernel_launch(void* const* d_in, const int* in_sizes, int n_in,
                              void* d_out, int out_size, void* d_ws, size_t ws_size,
                              hipStream_t stream) {
  const float* xyz1 = (const float*)d_in[0];
  const float* xyz2 = (const float*)d_in[1];
  const float* f1   = (const float*)d_in[2];
  const float* f2   = (const float*)d_in[3];
  const float* W1   = (const float*)d_in[4];
  const float* b1   = (const float*)d_in[5];
  const float* W2   = (const float*)d_in[6];
  const float* b2   = (const float*)d_in[7];
  float* out = (float*)d_out;

  const size_t NQ = (size_t)BDIM * N1;  // 65536
  char* ws = (char*)d_ws;
  bf16_t* W1t = (bf16_t*)ws;                         // 192 KB
  bf16_t* W2t = (bf16_t*)(ws + (256 << 10));         // 64 KB
  float*  wq  = (float*)(ws + (512 << 10));          // 768 KB
  int*    iq  = (int*)(ws + (1536 << 10));           // 768 KB
  // NF region (48 MB) now unused; offsets kept identical to validated layout.
  char*   hb  = ws + (2560 << 10) + NQ * CIN * 2;
  bf16_t* Hbuf  = (bf16_t*)hb;
  // candidates alias Hbuf (consumed by merge before interp_gemm1 writes Hbuf)
  float*  candd = (float*)hb;                        // 6.3 MB
  int*    candj = (int*)(hb + NQ * NCAND * 4);       // 6.3 MB

  prep_w<<<dim3(384), dim3(256), 0, stream>>>(W1, W2, W1t, W2t);
  knn_chunk<<<dim3(N1 / 256, BDIM, NCHUNK), dim3(256), 0, stream>>>(
      xyz1, xyz2, candd, candj);
  knn_merge<<<dim3(NQ / 256), dim3(256), 0, stream>>>(candd, candj, wq, iq);
  interp_gemm1<<<dim3(NQ / 128), dim3(256), 0, stream>>>(
      f1, f2, wq, iq, W1t, b1, Hbuf);
  gemm_bt<false><<<dim3(NQ / 128, HD2 / 128), dim3(256), 0, stream>>>(
      Hbuf, W2t, b2, (void*)out, NQ, HD2, HD1);
}